// Round 26
// baseline (950.799 us; speedup 1.0000x reference)
//
#include <hip/hip_runtime.h>

#define NN 512
#define NM1 511
#define PCT(r, j) pcT[(r) * 13 + (j)]
// bank-staggered lane-packed multiplier layout: step T, lane LL holds
// float4(l_row_LL, l_row_LL+64, l_row_LL+128, l_row_LL+192) at floats offset
// T*288 + 4*LL + 4*(LL>>3). Max offset 4*63+4*7+3 = 287 < 288 -> per-step
// slots DISJOINT (r25 bug: stride 272 made lanes 61-63 alias step T+1).
// Each 8-lane group shifted one bank -> wave64 b128 touches all 32 banks 8x.
#define LKI(T, LL) ((T) * 288 + 4 * (LL) + 4 * ((LL) >> 3))

// X-macros: T4x16(X) expands X(K,M) for K=0..3 (row group), M=0..15 (col)
#define T16(X, K) X(K,0) X(K,1) X(K,2) X(K,3) X(K,4) X(K,5) X(K,6) X(K,7) \
  X(K,8) X(K,9) X(K,10) X(K,11) X(K,12) X(K,13) X(K,14) X(K,15)
#define T4x16(X) T16(X,0) T16(X,1) T16(X,2) T16(X,3)
#define T16S(X) X(0) X(1) X(2) X(3) X(4) X(5) X(6) X(7) \
  X(8) X(9) X(10) X(11) X(12) X(13) X(14) X(15)
#define P8(X, K) X(K,0) X(K,1) X(K,2) X(K,3) X(K,4) X(K,5) X(K,6) X(K,7)
#define P4x8(X) P8(X,0) P8(X,1) P8(X,2) P8(X,3)

// readlane: value of v at (uniform) lane l -> scalar
__device__ __forceinline__ float rdlane(float v, int l) {
  return __uint_as_float(
      (unsigned)__builtin_amdgcn_readlane((int)__float_as_uint(v), l));
}
// fast reciprocal: v_rcp_f32 (~1 ulp); det still multiplies the EXACT pivot
__device__ __forceinline__ float fastrcp(float v) {
  float r;
  asm("v_rcp_f32 %0, %1" : "=v"(r) : "v"(v));
  return r;
}

// One block per matrix (1024 blocks), 1024 threads (16 waves), 1 block/CU via
// LDS pad + waves_per_eu(4,4) -> 128-reg budget.
// r26 = r25 (LDS-pipe diet: lane-packed float4 multipliers) with the stride
// bug fixed (272 -> 288; r25's slots aliased across steps -> absmax 13249).
// Base r24 structure: lookahead + half-TUT seed + setprio. TUT's 32 scalar
// b32 multiplier reads/wave/panel -> 8 conflict-free b128; FSTEP's 4 b32
// writes -> 1 b128 (shortens wave 0's serial chain). U-solve re-indexes only.
__global__ __attribute__((amdgpu_waves_per_eu(4, 4))) __launch_bounds__(1024)
void det_lu_kernel(
    const float* __restrict__ x,
    const float* __restrict__ F,
    float* __restrict__ out) {
  __shared__ __align__(16) float pcT[256 * 13];   // panel cols, row-major pad 13
  __shared__ __align__(16) float lbufD[2][8 * 288]; // multipliers (packed, dbuf)
  __shared__ __align__(16) float UbufD[2][8 * 260]; // pivot rows (dbuf)
  __shared__ float livef[256];
  __shared__ int   perm[256];
  __shared__ int   upbuf[256];
  __shared__ int   dnbuf[256];
  __shared__ int   wavecnt[8];
  __shared__ int   totinv;
  __shared__ float ldspad[7400];    // LDS total > 80KiB -> exactly 1 block/CU

  const int tid = threadIdx.x;
  const int L   = tid & 63;       // lane
  const int w   = tid >> 6;       // wave, owns cols [16w, 16w+16)

  const float* xrow = x + (size_t)blockIdx.x * NN;

  // keep ldspad referenced (opaque never-true condition)
  if ((int)blockIdx.x < 0) ((volatile float*)ldspad)[tid] = 1.0f;

  // ---- rank the +/-1 pattern: up = x>0 positions, dn = x<=0 positions
  bool pos = false;
  unsigned long long mask = 0;
  if (tid < NN) {
    float xv = xrow[tid];
    pos = xv > 0.0f;
    mask = __ballot(pos);           // waves 0-7 fully active
    if (L == 0) wavecnt[w] = __popcll(mask);
  }
  if (tid == 0) totinv = 0;
  if (tid < 256) livef[tid] = 1.0f;
  __syncthreads();
  if (tid < NN) {
    int base = 0;
    for (int i = 0; i < w; i++) base += wavecnt[i];
    int pbelow = __popcll(mask & ((1ull << L) - 1ull));
    if (pos) upbuf[base + pbelow] = tid;
    else     dnbuf[(64 * w - base) + (L - pbelow)] = tid;
  }
  __syncthreads();

  // ---- gather tile into 64 named scalars: aK_M = sub[L+64K][16w+M]
#define DECLC(M) const int cg##M = dnbuf[16 * w + (M)];
  T16S(DECLC)
  const int rg0 = upbuf[L];
  const int rg1 = upbuf[L + 64];
  const int rg2 = upbuf[L + 128];
  const int rg3 = upbuf[L + 192];
#define DECLA(K, M)                                                         \
  float a##K##_##M = (cg##M == rg##K)                                       \
      ? 0.0f                                                                \
      : F[(size_t)rg##K * NM1 + cg##M - (cg##M > rg##K ? 1 : 0)];
  T4x16(DECLA)

  // ---- seed panel 0: wave 0 (owns cols 0..15) writes PCT[row][0..7]
  if (w == 0) {
#define S0(K, M) if ((M) < 8) PCT(L + 64 * (K), (M)) = a##K##_##M;
    T4x16(S0)
  }
  double det = 1.0;
  __syncthreads();   // barrier A (panel 0 seeded)

  // ======================= panel factor-step machinery (wave 0) ===========
#define DPPMAX(CTRL) {                                                      \
    unsigned _t = (unsigned)__builtin_amdgcn_update_dpp(                    \
        0, (int)key, (CTRL), 0xf, 0xf, false);                              \
    key = key > _t ? key : _t; }
#define BCJ(K, J, S) if ((J) >= (S)) uv##J = rdlane(pr##K##_##J, lp);
#define BCARM(K, S)                                                         \
    if (kp == (K)) { BCJ(K,0,S) BCJ(K,1,S) BCJ(K,2,S) BCJ(K,3,S)            \
                     BCJ(K,4,S) BCJ(K,5,S) BCJ(K,6,S) BCJ(K,7,S) }
#define LSTEP(K, S)                                                         \
    float l##K = ((dead4 >> (K)) & 1u) ? 0.0f : pr##K##_##S * invp;         \
    pr##K##_##S = l##K;
#define UPD(K, J, S)                                                        \
    if ((J) > (S)) pr##K##_##J = fmaf(-l##K, uv##J, pr##K##_##J);
#define UPDJ(J, S) UPD(0,J,S) UPD(1,J,S) UPD(2,J,S) UPD(3,J,S)
#define FSTEP(S) {                                                          \
    unsigned b0 = (dead4 & 1u) ? 0u                                         \
        : ((__float_as_uint(fabsf(pr0_##S)) & 0xFFFFFF00u) | (unsigned)L);  \
    unsigned b1 = (dead4 & 2u) ? 0u                                         \
        : ((__float_as_uint(fabsf(pr1_##S)) & 0xFFFFFF00u) | (unsigned)(L + 64)); \
    unsigned b2 = (dead4 & 4u) ? 0u                                         \
        : ((__float_as_uint(fabsf(pr2_##S)) & 0xFFFFFF00u) | (unsigned)(L + 128)); \
    unsigned b3 = (dead4 & 8u) ? 0u                                         \
        : ((__float_as_uint(fabsf(pr3_##S)) & 0xFFFFFF00u) | (unsigned)(L + 192)); \
    unsigned m01 = b0 > b1 ? b0 : b1, m23 = b2 > b3 ? b2 : b3;              \
    unsigned key = m01 > m23 ? m01 : m23;                                   \
    DPPMAX(0x111) DPPMAX(0x112) DPPMAX(0x114) DPPMAX(0x118)                 \
    DPPMAX(0x142) DPPMAX(0x143)                                             \
    const int pv = __builtin_amdgcn_readlane((int)key, 63) & 255;           \
    const int kp = pv >> 6, lp = pv & 63;                                   \
    if (lp == L) dead4 |= 1u << kp;                                         \
    float uv0 = 0.f, uv1 = 0.f, uv2 = 0.f, uv3 = 0.f;                       \
    float uv4 = 0.f, uv5 = 0.f, uv6 = 0.f, uv7 = 0.f;                       \
    BCARM(0,S) BCARM(1,S) BCARM(2,S) BCARM(3,S)                             \
    const float piv = uv##S;                                                \
    det *= (double)piv;                                                     \
    const float invp = fastrcp(piv);                                        \
    LSTEP(0,S) LSTEP(1,S) LSTEP(2,S) LSTEP(3,S)                             \
    UPDJ(0,S) UPDJ(1,S) UPDJ(2,S) UPDJ(3,S)                                 \
    UPDJ(4,S) UPDJ(5,S) UPDJ(6,S) UPDJ(7,S)                                 \
    *reinterpret_cast<float4*>(&lbP[LKI(S, L)]) =                           \
        make_float4(l0, l1, l2, l3);                                        \
    if (L == lp) livef[pv] = 0.0f;                                          \
    if (L == 0) perm[P * 8 + (S)] = pv;                                     \
  }

  // ---- post-barrier stash of raw pivot row T (own 16-col strip, into ubP)
#define STQW(T, K)                                                          \
    if (L == (p##T & 63)) {                                                 \
      float* ubw = &ubP[(T) * 260 + 16 * w];                                \
      *reinterpret_cast<float4*>(ubw + 0) =                                 \
          make_float4(a##K##_0, a##K##_1, a##K##_2, a##K##_3);              \
      *reinterpret_cast<float4*>(ubw + 4) =                                 \
          make_float4(a##K##_4, a##K##_5, a##K##_6, a##K##_7);              \
      *reinterpret_cast<float4*>(ubw + 8) =                                 \
          make_float4(a##K##_8, a##K##_9, a##K##_10, a##K##_11);            \
      *reinterpret_cast<float4*>(ubw + 12) =                                \
          make_float4(a##K##_12, a##K##_13, a##K##_14, a##K##_15);          \
    }
#define STASHT(T) {                                                         \
    const int kpt = p##T >> 6;                                              \
    if (kpt == 0)      { STQW(T, 0) }                                       \
    else if (kpt == 1) { STQW(T, 1) }                                       \
    else if (kpt == 2) { STQW(T, 2) }                                       \
    else               { STQW(T, 3) }                                       \
  }

  // trailing update body: A_K_M -= sum_t lk_K[t] * U[t][M]; quad-selectable
#define TUROW(K, A, B, C, D)                                                \
    a##K##_##A = fmaf(-lk##K, uq.x, a##K##_##A);                            \
    a##K##_##B = fmaf(-lk##K, uq.y, a##K##_##B);                            \
    a##K##_##C = fmaf(-lk##K, uq.z, a##K##_##C);                            \
    a##K##_##D = fmaf(-lk##K, uq.w, a##K##_##D);
#define TUQ(A, B, C, D)                                                     \
    TUROW(0, A, B, C, D) TUROW(1, A, B, C, D)                               \
    TUROW(2, A, B, C, D) TUROW(3, A, B, C, D)
#define TUTCORE(LB_, UB_, Q0_, Q1_, Q2_, Q3_)                               \
    _Pragma("unroll 2")                                                     \
    for (int t = 0; t < 8; t++) {                                           \
      const float4 lk4 =                                                    \
          *reinterpret_cast<const float4*>(&(LB_)[LKI(t, L)]);              \
      const float lk0 = lk4.x, lk1 = lk4.y, lk2 = lk4.z, lk3 = lk4.w;       \
      const float* ub_ = &(UB_)[t * 260 + 16 * w];                          \
      if (Q0_) { const float4 uq = *reinterpret_cast<const float4*>(ub_ + 0);  \
        TUQ(0, 1, 2, 3) }                                                   \
      if (Q1_) { const float4 uq = *reinterpret_cast<const float4*>(ub_ + 4);  \
        TUQ(4, 5, 6, 7) }                                                   \
      if (Q2_) { const float4 uq = *reinterpret_cast<const float4*>(ub_ + 8);  \
        TUQ(8, 9, 10, 11) }                                                 \
      if (Q3_) { const float4 uq = *reinterpret_cast<const float4*>(ub_ + 12); \
        TUQ(12, 13, 14, 15) }                                               \
    }
#define TUTLOOP(LB_, UB_) TUTCORE(LB_, UB_, 1, 1, 1, 1)
#define TUTLO(LB_, UB_)   TUTCORE(LB_, UB_, 1, 1, 0, 0)
#define TUTHI(LB_, UB_)   TUTCORE(LB_, UB_, 0, 0, 1, 1)

  // ---- panel loop with lookahead (barriers at uniform top level ONLY)
#pragma unroll 1
  for (int P = 0; P < 32; P++) {
    const int bsel = P & 1;
    float* const lbP = lbufD[bsel];          // panel P multipliers (packed)
    float* const ubP = UbufD[bsel];          // panel P pivot rows
    const float* const lbQ = lbufD[bsel ^ 1]; // panel P-1
    const float* const ubQ = UbufD[bsel ^ 1];
    const bool trailingP = (2 * w + 1 > P);  // wave-uniform: live at P

    // -------- phase 1: factor(P) on wave 0 || deferred TUT(P-1) on others
    if (w == 0) {
      __builtin_amdgcn_s_setprio(1);   // critical serial chain
#define LDP(K, J) float pr##K##_##J = PCT(L + 64 * (K), (J));
      P4x8(LDP)
      unsigned dead4 = 0u;
      FSTEP(0) FSTEP(1) FSTEP(2) FSTEP(3)
      FSTEP(4) FSTEP(5) FSTEP(6) FSTEP(7)
      __builtin_amdgcn_s_setprio(0);
    } else if (P > 0 && w > (P >> 1)) {
      TUTLOOP(lbQ, ubQ)                  // plain trailing: full TUT(P-1)
    } else if (P > 0 && w == (P >> 1) && (P & 1) == 0) {
      TUTHI(lbQ, ubQ)                    // seed-wave leftover: hi half only
    }
    __syncthreads();   // barrier B: lbP/livef/perm visible; TUT(P-1) done

    // -------- phase 2: stash + per-wave U-solve (trailing waves);
    //                   seed wave: early HALF TUT(P) + seed panel P+1
    const int wstar = (P + 1) >> 1;
    const bool isSeed = (P < 31 && w == wstar);   // wave-uniform
    if (isSeed) __builtin_amdgcn_s_setprio(1);    // phase-2 straggler
    if (trailingP) {
      const int p0 = perm[P * 8 + 0], p1 = perm[P * 8 + 1];
      const int p2 = perm[P * 8 + 2], p3 = perm[P * 8 + 3];
      const int p4 = perm[P * 8 + 4], p5 = perm[P * 8 + 5];
      const int p6 = perm[P * 8 + 6], p7 = perm[P * 8 + 7];
      STASHT(0) STASHT(1) STASHT(2) STASHT(3)
      STASHT(4) STASHT(5) STASHT(6) STASHT(7)
      asm volatile("s_waitcnt lgkmcnt(0)" ::: "memory");
      if (L < 16) {            // per-wave U-solve on OWN 16-col strip
        const int jb = 16 * w + L;
        float u[8];
#pragma unroll
        for (int t = 0; t < 8; t++) {
          const int pt = perm[P * 8 + t];
          float acc = ubP[t * 260 + jb];
#pragma unroll
          for (int s2 = 0; s2 < t; s2++)
            acc = fmaf(-lbP[LKI(s2, pt & 63) + (pt >> 6)], u[s2], acc);
          u[t] = acc;
          ubP[t * 260 + jb] = acc;
        }
      }
      asm volatile("s_waitcnt lgkmcnt(0)" ::: "memory");
    }
    {
      const int h = (P + 1) & 1;
      if (isSeed) {                      // seed wave is always trailingP
        const float lv0 = livef[L];
        const float lv1 = livef[L + 64];
        const float lv2 = livef[L + 128];
        const float lv3 = livef[L + 192];
#define SEa(K, M) if ((M) < 8)  PCT(L + 64*(K), (M))     = a##K##_##M * lv##K;
#define SEb(K, M) if ((M) >= 8) PCT(L + 64*(K), (M) - 8) = a##K##_##M * lv##K;
        if (h == 0) { TUTLO(lbP, ubP) T4x16(SEa) }
        else        { TUTHI(lbP, ubP) T4x16(SEb) }
        __builtin_amdgcn_s_setprio(0);
      }
    }
    __syncthreads();   // barrier A: next panel seeded; ubP/stash complete
  }

  // ---- permutation parity via parallel inversion count (1024-thread map)
  int myinv = 0;
  {
    const int i0 = tid & 255;
    const int cbase = (tid >> 8) * 64;
    const int pi = perm[i0];
#pragma unroll 8
    for (int j = 0; j < 64; j++) {
      int jj = cbase + j;
      if (jj > i0 && perm[jj] < pi) myinv++;
    }
  }
#pragma unroll
  for (int off = 32; off; off >>= 1) myinv += __shfl_xor(myinv, off);
  if (L == 0) atomicAdd(&totinv, myinv);
  __syncthreads();
  if (tid == 0) out[blockIdx.x] = (float)((totinv & 1) ? -det : det);
}

extern "C" void kernel_launch(void* const* d_in, const int* in_sizes, int n_in,
                              void* d_out, int out_size, void* d_ws, size_t ws_size,
                              hipStream_t stream) {
  const float* x = (const float*)d_in[0];   // (1024, 512) fp32
  const float* F = (const float*)d_in[1];   // (512*512-512,) fp32
  float* out = (float*)d_out;               // (1024,) fp32
  const int B = out_size;                   // 1024
  hipLaunchKernelGGL(det_lu_kernel, dim3(B), dim3(1024), 0, stream, x, F, out);
}

// Round 27
// 906.177 us; speedup vs baseline: 1.0492x; 1.0492x over previous
//
#include <hip/hip_runtime.h>

#define NN 512
#define NM1 511
#define PCT(r, j) pcT[(r) * 13 + (j)]

// X-macros: T4x16(X) expands X(K,M) for K=0..3 (row group), M=0..15 (col)
#define T16(X, K) X(K,0) X(K,1) X(K,2) X(K,3) X(K,4) X(K,5) X(K,6) X(K,7) \
  X(K,8) X(K,9) X(K,10) X(K,11) X(K,12) X(K,13) X(K,14) X(K,15)
#define T4x16(X) T16(X,0) T16(X,1) T16(X,2) T16(X,3)
#define T16S(X) X(0) X(1) X(2) X(3) X(4) X(5) X(6) X(7) \
  X(8) X(9) X(10) X(11) X(12) X(13) X(14) X(15)
#define P8(X, K) X(K,0) X(K,1) X(K,2) X(K,3) X(K,4) X(K,5) X(K,6) X(K,7)
#define P4x8(X) P8(X,0) P8(X,1) P8(X,2) P8(X,3)

// readlane: value of v at (uniform) lane l -> scalar
__device__ __forceinline__ float rdlane(float v, int l) {
  return __uint_as_float(
      (unsigned)__builtin_amdgcn_readlane((int)__float_as_uint(v), l));
}
// fast reciprocal: v_rcp_f32 (~1 ulp); det still multiplies the EXACT pivot
__device__ __forceinline__ float fastrcp(float v) {
  float r;
  asm("v_rcp_f32 %0, %1" : "=v"(r) : "v"(v));
  return r;
}

// One block per matrix (1024 blocks), 1024 threads (16 waves), 1 block/CU via
// LDS pad + waves_per_eu(4,4) -> 128-reg budget.
// FINAL (r24, 905us verified): lookahead (factor(P) on wave 0 || deferred
// TUT(P-1) on other waves) + half-TUT seed path + per-wave U-solve on own
// strip + post-barrier stash + fastrcp + setprio on straggler waves.
// Scalar lbuf reads are stride-1 conflict-free (r26's float4 repack measured
// 8.9M bank conflicts and regressed — reverted). Nothing lives across
// barriers beyond the a-tile (r15-r17 proved any extra spills).
__global__ __attribute__((amdgpu_waves_per_eu(4, 4))) __launch_bounds__(1024)
void det_lu_kernel(
    const float* __restrict__ x,
    const float* __restrict__ F,
    float* __restrict__ out) {
  __shared__ __align__(16) float pcT[256 * 13];   // panel cols, row-major pad 13
  __shared__ __align__(16) float lbufD[2][8 * 256]; // multipliers (dbuf)
  __shared__ __align__(16) float UbufD[2][8 * 260]; // pivot rows (dbuf)
  __shared__ float livef[256];
  __shared__ int   perm[256];
  __shared__ int   upbuf[256];
  __shared__ int   dnbuf[256];
  __shared__ int   wavecnt[8];
  __shared__ int   totinv;
  __shared__ float ldspad[7900];    // LDS total > 80KiB -> exactly 1 block/CU

  const int tid = threadIdx.x;
  const int L   = tid & 63;       // lane
  const int w   = tid >> 6;       // wave, owns cols [16w, 16w+16)

  const float* xrow = x + (size_t)blockIdx.x * NN;

  // keep ldspad referenced (opaque never-true condition)
  if ((int)blockIdx.x < 0) ((volatile float*)ldspad)[tid] = 1.0f;

  // ---- rank the +/-1 pattern: up = x>0 positions, dn = x<=0 positions
  bool pos = false;
  unsigned long long mask = 0;
  if (tid < NN) {
    float xv = xrow[tid];
    pos = xv > 0.0f;
    mask = __ballot(pos);           // waves 0-7 fully active
    if (L == 0) wavecnt[w] = __popcll(mask);
  }
  if (tid == 0) totinv = 0;
  if (tid < 256) livef[tid] = 1.0f;
  __syncthreads();
  if (tid < NN) {
    int base = 0;
    for (int i = 0; i < w; i++) base += wavecnt[i];
    int pbelow = __popcll(mask & ((1ull << L) - 1ull));
    if (pos) upbuf[base + pbelow] = tid;
    else     dnbuf[(64 * w - base) + (L - pbelow)] = tid;
  }
  __syncthreads();

  // ---- gather tile into 64 named scalars: aK_M = sub[L+64K][16w+M]
#define DECLC(M) const int cg##M = dnbuf[16 * w + (M)];
  T16S(DECLC)
  const int rg0 = upbuf[L];
  const int rg1 = upbuf[L + 64];
  const int rg2 = upbuf[L + 128];
  const int rg3 = upbuf[L + 192];
#define DECLA(K, M)                                                         \
  float a##K##_##M = (cg##M == rg##K)                                       \
      ? 0.0f                                                                \
      : F[(size_t)rg##K * NM1 + cg##M - (cg##M > rg##K ? 1 : 0)];
  T4x16(DECLA)

  // ---- seed panel 0: wave 0 (owns cols 0..15) writes PCT[row][0..7]
  if (w == 0) {
#define S0(K, M) if ((M) < 8) PCT(L + 64 * (K), (M)) = a##K##_##M;
    T4x16(S0)
  }
  double det = 1.0;
  __syncthreads();   // barrier A (panel 0 seeded)

  // ======================= panel factor-step machinery (wave 0) ===========
#define DPPMAX(CTRL) {                                                      \
    unsigned _t = (unsigned)__builtin_amdgcn_update_dpp(                    \
        0, (int)key, (CTRL), 0xf, 0xf, false);                              \
    key = key > _t ? key : _t; }
#define BCJ(K, J, S) if ((J) >= (S)) uv##J = rdlane(pr##K##_##J, lp);
#define BCARM(K, S)                                                         \
    if (kp == (K)) { BCJ(K,0,S) BCJ(K,1,S) BCJ(K,2,S) BCJ(K,3,S)            \
                     BCJ(K,4,S) BCJ(K,5,S) BCJ(K,6,S) BCJ(K,7,S) }
#define LSTEP(K, S)                                                         \
    float l##K = ((dead4 >> (K)) & 1u) ? 0.0f : pr##K##_##S * invp;         \
    pr##K##_##S = l##K;
#define UPD(K, J, S)                                                        \
    if ((J) > (S)) pr##K##_##J = fmaf(-l##K, uv##J, pr##K##_##J);
#define UPDJ(J, S) UPD(0,J,S) UPD(1,J,S) UPD(2,J,S) UPD(3,J,S)
#define FSTEP(S) {                                                          \
    unsigned b0 = (dead4 & 1u) ? 0u                                         \
        : ((__float_as_uint(fabsf(pr0_##S)) & 0xFFFFFF00u) | (unsigned)L);  \
    unsigned b1 = (dead4 & 2u) ? 0u                                         \
        : ((__float_as_uint(fabsf(pr1_##S)) & 0xFFFFFF00u) | (unsigned)(L + 64)); \
    unsigned b2 = (dead4 & 4u) ? 0u                                         \
        : ((__float_as_uint(fabsf(pr2_##S)) & 0xFFFFFF00u) | (unsigned)(L + 128)); \
    unsigned b3 = (dead4 & 8u) ? 0u                                         \
        : ((__float_as_uint(fabsf(pr3_##S)) & 0xFFFFFF00u) | (unsigned)(L + 192)); \
    unsigned m01 = b0 > b1 ? b0 : b1, m23 = b2 > b3 ? b2 : b3;              \
    unsigned key = m01 > m23 ? m01 : m23;                                   \
    DPPMAX(0x111) DPPMAX(0x112) DPPMAX(0x114) DPPMAX(0x118)                 \
    DPPMAX(0x142) DPPMAX(0x143)                                             \
    const int pv = __builtin_amdgcn_readlane((int)key, 63) & 255;           \
    const int kp = pv >> 6, lp = pv & 63;                                   \
    if (lp == L) dead4 |= 1u << kp;                                         \
    float uv0 = 0.f, uv1 = 0.f, uv2 = 0.f, uv3 = 0.f;                       \
    float uv4 = 0.f, uv5 = 0.f, uv6 = 0.f, uv7 = 0.f;                       \
    BCARM(0,S) BCARM(1,S) BCARM(2,S) BCARM(3,S)                             \
    const float piv = uv##S;                                                \
    det *= (double)piv;                                                     \
    const float invp = fastrcp(piv);                                        \
    LSTEP(0,S) LSTEP(1,S) LSTEP(2,S) LSTEP(3,S)                             \
    UPDJ(0,S) UPDJ(1,S) UPDJ(2,S) UPDJ(3,S)                                 \
    UPDJ(4,S) UPDJ(5,S) UPDJ(6,S) UPDJ(7,S)                                 \
    lbP[(S) * 256 + L      ] = l0;                                          \
    lbP[(S) * 256 + L +  64] = l1;                                          \
    lbP[(S) * 256 + L + 128] = l2;                                          \
    lbP[(S) * 256 + L + 192] = l3;                                          \
    if (L == lp) livef[pv] = 0.0f;                                          \
    if (L == 0) perm[P * 8 + (S)] = pv;                                     \
  }

  // ---- post-barrier stash of raw pivot row T (own 16-col strip, into ubP)
#define STQW(T, K)                                                          \
    if (L == (p##T & 63)) {                                                 \
      float* ubw = &ubP[(T) * 260 + 16 * w];                                \
      *reinterpret_cast<float4*>(ubw + 0) =                                 \
          make_float4(a##K##_0, a##K##_1, a##K##_2, a##K##_3);              \
      *reinterpret_cast<float4*>(ubw + 4) =                                 \
          make_float4(a##K##_4, a##K##_5, a##K##_6, a##K##_7);              \
      *reinterpret_cast<float4*>(ubw + 8) =                                 \
          make_float4(a##K##_8, a##K##_9, a##K##_10, a##K##_11);            \
      *reinterpret_cast<float4*>(ubw + 12) =                                \
          make_float4(a##K##_12, a##K##_13, a##K##_14, a##K##_15);          \
    }
#define STASHT(T) {                                                         \
    const int kpt = p##T >> 6;                                              \
    if (kpt == 0)      { STQW(T, 0) }                                       \
    else if (kpt == 1) { STQW(T, 1) }                                       \
    else if (kpt == 2) { STQW(T, 2) }                                       \
    else               { STQW(T, 3) }                                       \
  }

  // trailing update body: A_K_M -= sum_t lk_K[t] * U[t][M]; quad-selectable
#define TUROW(K, A, B, C, D)                                                \
    a##K##_##A = fmaf(-lk##K, uq.x, a##K##_##A);                            \
    a##K##_##B = fmaf(-lk##K, uq.y, a##K##_##B);                            \
    a##K##_##C = fmaf(-lk##K, uq.z, a##K##_##C);                            \
    a##K##_##D = fmaf(-lk##K, uq.w, a##K##_##D);
#define TUQ(A, B, C, D)                                                     \
    TUROW(0, A, B, C, D) TUROW(1, A, B, C, D)                               \
    TUROW(2, A, B, C, D) TUROW(3, A, B, C, D)
#define TUTCORE(LB_, UB_, Q0_, Q1_, Q2_, Q3_)                               \
    _Pragma("unroll 2")                                                     \
    for (int t = 0; t < 8; t++) {                                           \
      const float lk0 = (LB_)[t * 256 + L];                                 \
      const float lk1 = (LB_)[t * 256 + L + 64];                            \
      const float lk2 = (LB_)[t * 256 + L + 128];                           \
      const float lk3 = (LB_)[t * 256 + L + 192];                           \
      const float* ub_ = &(UB_)[t * 260 + 16 * w];                          \
      if (Q0_) { const float4 uq = *reinterpret_cast<const float4*>(ub_ + 0);  \
        TUQ(0, 1, 2, 3) }                                                   \
      if (Q1_) { const float4 uq = *reinterpret_cast<const float4*>(ub_ + 4);  \
        TUQ(4, 5, 6, 7) }                                                   \
      if (Q2_) { const float4 uq = *reinterpret_cast<const float4*>(ub_ + 8);  \
        TUQ(8, 9, 10, 11) }                                                 \
      if (Q3_) { const float4 uq = *reinterpret_cast<const float4*>(ub_ + 12); \
        TUQ(12, 13, 14, 15) }                                               \
    }
#define TUTLOOP(LB_, UB_) TUTCORE(LB_, UB_, 1, 1, 1, 1)
#define TUTLO(LB_, UB_)   TUTCORE(LB_, UB_, 1, 1, 0, 0)
#define TUTHI(LB_, UB_)   TUTCORE(LB_, UB_, 0, 0, 1, 1)

  // ---- panel loop with lookahead (barriers at uniform top level ONLY)
#pragma unroll 1
  for (int P = 0; P < 32; P++) {
    const int bsel = P & 1;
    float* const lbP = lbufD[bsel];          // panel P multipliers
    float* const ubP = UbufD[bsel];          // panel P pivot rows
    const float* const lbQ = lbufD[bsel ^ 1]; // panel P-1
    const float* const ubQ = UbufD[bsel ^ 1];
    const bool trailingP = (2 * w + 1 > P);  // wave-uniform: live at P

    // -------- phase 1: factor(P) on wave 0 || deferred TUT(P-1) on others
    if (w == 0) {
      __builtin_amdgcn_s_setprio(1);   // critical serial chain
#define LDP(K, J) float pr##K##_##J = PCT(L + 64 * (K), (J));
      P4x8(LDP)
      unsigned dead4 = 0u;
      FSTEP(0) FSTEP(1) FSTEP(2) FSTEP(3)
      FSTEP(4) FSTEP(5) FSTEP(6) FSTEP(7)
      __builtin_amdgcn_s_setprio(0);
    } else if (P > 0 && w > (P >> 1)) {
      TUTLOOP(lbQ, ubQ)                  // plain trailing: full TUT(P-1)
    } else if (P > 0 && w == (P >> 1) && (P & 1) == 0) {
      TUTHI(lbQ, ubQ)                    // seed-wave leftover: hi half only
    }
    __syncthreads();   // barrier B: lbP/livef/perm visible; TUT(P-1) done

    // -------- phase 2: stash + per-wave U-solve (trailing waves);
    //                   seed wave: early HALF TUT(P) + seed panel P+1
    const int wstar = (P + 1) >> 1;
    const bool isSeed = (P < 31 && w == wstar);   // wave-uniform
    if (isSeed) __builtin_amdgcn_s_setprio(1);    // phase-2 straggler
    if (trailingP) {
      const int p0 = perm[P * 8 + 0], p1 = perm[P * 8 + 1];
      const int p2 = perm[P * 8 + 2], p3 = perm[P * 8 + 3];
      const int p4 = perm[P * 8 + 4], p5 = perm[P * 8 + 5];
      const int p6 = perm[P * 8 + 6], p7 = perm[P * 8 + 7];
      STASHT(0) STASHT(1) STASHT(2) STASHT(3)
      STASHT(4) STASHT(5) STASHT(6) STASHT(7)
      asm volatile("s_waitcnt lgkmcnt(0)" ::: "memory");
      if (L < 16) {            // per-wave U-solve on OWN 16-col strip
        const int jb = 16 * w + L;
        float u[8];
#pragma unroll
        for (int t = 0; t < 8; t++) {
          const int pt = perm[P * 8 + t];
          float acc = ubP[t * 260 + jb];
#pragma unroll
          for (int s2 = 0; s2 < t; s2++)
            acc = fmaf(-lbP[s2 * 256 + pt], u[s2], acc);
          u[t] = acc;
          ubP[t * 260 + jb] = acc;
        }
      }
      asm volatile("s_waitcnt lgkmcnt(0)" ::: "memory");
    }
    {
      const int h = (P + 1) & 1;
      if (isSeed) {                      // seed wave is always trailingP
        const float lv0 = livef[L];
        const float lv1 = livef[L + 64];
        const float lv2 = livef[L + 128];
        const float lv3 = livef[L + 192];
#define SEa(K, M) if ((M) < 8)  PCT(L + 64*(K), (M))     = a##K##_##M * lv##K;
#define SEb(K, M) if ((M) >= 8) PCT(L + 64*(K), (M) - 8) = a##K##_##M * lv##K;
        if (h == 0) { TUTLO(lbP, ubP) T4x16(SEa) }
        else        { TUTHI(lbP, ubP) T4x16(SEb) }
        __builtin_amdgcn_s_setprio(0);
      }
    }
    __syncthreads();   // barrier A: next panel seeded; ubP/stash complete
  }

  // ---- permutation parity via parallel inversion count (1024-thread map)
  int myinv = 0;
  {
    const int i0 = tid & 255;
    const int cbase = (tid >> 8) * 64;
    const int pi = perm[i0];
#pragma unroll 8
    for (int j = 0; j < 64; j++) {
      int jj = cbase + j;
      if (jj > i0 && perm[jj] < pi) myinv++;
    }
  }
#pragma unroll
  for (int off = 32; off; off >>= 1) myinv += __shfl_xor(myinv, off);
  if (L == 0) atomicAdd(&totinv, myinv);
  __syncthreads();
  if (tid == 0) out[blockIdx.x] = (float)((totinv & 1) ? -det : det);
}

extern "C" void kernel_launch(void* const* d_in, const int* in_sizes, int n_in,
                              void* d_out, int out_size, void* d_ws, size_t ws_size,
                              hipStream_t stream) {
  const float* x = (const float*)d_in[0];   // (1024, 512) fp32
  const float* F = (const float*)d_in[1];   // (512*512-512,) fp32
  float* out = (float*)d_out;               // (1024,) fp32
  const int B = out_size;                   // 1024
  hipLaunchKernelGGL(det_lu_kernel, dim3(B), dim3(1024), 0, stream, x, F, out);
}